// Round 6
// baseline (48.472 us; speedup 1.0000x reference)
//
#include <hip/hip_runtime.h>
#include <cstddef>

namespace {

constexpr int NB    = 8;
constexpr int LQn   = 2048;
constexpr int DM    = 256;
constexpr int S_TOT = 3840;   // 2048+1024+512+256

typedef __attribute__((ext_vector_type(8))) short  short8;
typedef __attribute__((ext_vector_type(4))) float  f32x4;
typedef __attribute__((ext_vector_type(8))) _Float16 half8;
typedef __attribute__((ext_vector_type(4))) _Float16 half4;
typedef __attribute__((ext_vector_type(2))) _Float16 half2v;

__device__ inline unsigned short f2bf(float f) {
  union { float f; unsigned u; } v; v.f = f;
  const unsigned u = v.u;
  return (unsigned short)((u + 0x7FFFu + ((u >> 16) & 1u)) >> 16);  // RNE
}

__device__ inline void load_lds16(const void* g, void* l) {
  __builtin_amdgcn_global_load_lds(
      (const __attribute__((address_space(1))) void*)g,
      (__attribute__((address_space(3))) void*)l, 16, 0, 0);
}

// ---------------------------------------------------------------------------
// W pre-convert: f32 weights -> bf16 blob in PRE-SWIZZLED LDS-image order.
// 16 tiles (which{val_c0,val_c1,off,attn} x 4 k-tiles) x 1024 chunks x 16B.
// Linear blob position p within a tile corresponds to lds_byte p*16 =
// row*128 + ((kg*16)^((row&7)<<4)); solving: row = p>>3, kg = (p&7)^(row&7).
// GEMM then linear-copies blob->LDS (global_load_lds) and reads with the
// standard T2 XOR formula (rule #21: source-permute == read-permute).
// ---------------------------------------------------------------------------
__global__ __launch_bounds__(256) void wconv_k(
    const float* __restrict__ W_val, const float* __restrict__ W_off,
    const float* __restrict__ W_att, unsigned short* __restrict__ blob)
{
  const int g     = blockIdx.x * 256 + threadIdx.x;   // 0..16383
  const int tile  = g >> 10;
  const int ch    = g & 1023;
  const int which = tile >> 2;
  const int kt    = tile & 3;
  const int row   = ch >> 3;
  const int kg    = (ch & 7) ^ (row & 7);
  const float* src;
  if (which == 0)      src = W_val + (size_t)row * DM;
  else if (which == 1) src = W_val + (size_t)(128 + row) * DM;
  else if (which == 2) src = W_off + (size_t)row * DM;
  else                 src = W_att + (size_t)row * DM;
  const int col = kt * 64 + kg * 8;
  const f32x4 w0 = *reinterpret_cast<const f32x4*>(&src[col]);
  const f32x4 w1 = *reinterpret_cast<const f32x4*>(&src[col + 4]);
  short8 s;
  #pragma unroll
  for (int j = 0; j < 4; ++j) {
    s[j]     = (short)f2bf(w0[j]);
    s[j + 4] = (short)f2bf(w1[j]);
  }
  *reinterpret_cast<short8*>(&blob[(size_t)g * 8]) = s;
}

// ---------------------------------------------------------------------------
// Merged bf16-MFMA GEMM (value + proj), f16 output. 1D grid of 736 blocks:
//   id <  480: value GEMM (240 row-blocks x 2 col-halves of W_val)
//   id >= 480: proj GEMM  (128 row-blocks x {W_off | W_attn})
// A: reg-staged with fused f32->bf16 convert (one-k-tile-ahead prefetch).
// B (W): staged from the pre-swizzled bf16 blob via global_load_lds w=16
//   (no registers, no converts, no ds_writes).
// Barrier discipline (T4 counted vmcnt): per k-step issue order is
//   [W gload_lds(k): 4] [A convert+ds_write (uses pa_k)] [A loads pa_{k+1}: 8]
//   s_waitcnt vmcnt(8) lgkmcnt(0)  -> W landed, A ds_writes done,
//                                      pa_{k+1}'s 8 loads STAY IN FLIGHT
//   raw s_barrier ... MFMA ... lgkmcnt(0) ... raw s_barrier.
// k=3 issues a redundant tile-0 prefetch so vmcnt(8) is uniform.
// ---------------------------------------------------------------------------
__global__ __launch_bounds__(256) void gemm_bf16_k(
    const float* __restrict__ A_val, const float* __restrict__ A_prj,
    const unsigned short* __restrict__ wblob,
    const float* __restrict__ b_val,
    const float* __restrict__ b_off, const float* __restrict__ b_att,
    _Float16* __restrict__ out_val, _Float16* __restrict__ out_prj)
{
  __shared__ short As[128 * 64];
  __shared__ short Bs[128 * 64];

  const int tid  = threadIdx.x;
  const int lane = tid & 63;
  const int wid  = tid >> 6;
  const int wm   = wid >> 1;
  const int wn   = wid & 1;

  const int id = blockIdx.x;
  const float* A;
  const float* bias;
  _Float16* out;
  int r0, c0, which;
  if (id < 480) {
    const int rb = id >> 1, c = id & 1;
    A = A_val; out = out_val; r0 = rb * 128; c0 = c * 128;
    which = c; bias = b_val + c * 128;
  } else {
    const int j = id - 480, rb = j >> 1, c = j & 1;
    A = A_prj; out = out_prj; r0 = rb * 128; c0 = c * 128;
    which = 2 + c; bias = c ? b_att : b_off;
  }
  const char* wbase = reinterpret_cast<const char*>(wblob) +
                      (size_t)which * 4 * 16384;

  f32x4 acc[4][4] = {};

  float bv[4];
  #pragma unroll
  for (int ni = 0; ni < 4; ++ni)
    bv[ni] = bias[wn * 64 + ni * 16 + (lane & 15)];

  f32x4 pa0[4], pa1[4];

  auto load_A = [&](int k0) {
    #pragma unroll
    for (int i = 0; i < 4; ++i) {
      const int ch  = tid + i * 256;   // 0..1023
      const int row = ch >> 3;         // 0..127
      const int kg  = ch & 7;          // 0..7
      const size_t goff = (size_t)(r0 + row) * DM + k0 + kg * 8;
      pa0[i] = *reinterpret_cast<const f32x4*>(&A[goff]);
      pa1[i] = *reinterpret_cast<const f32x4*>(&A[goff + 4]);
    }
  };

  load_A(0);

  #pragma unroll
  for (int k = 0; k < 4; ++k) {
    // ---- stage W tile k: linear blob -> linear LDS (image is pre-swizzled)
    {
      const char* wsrc = wbase + (size_t)k * 16384;
      #pragma unroll
      for (int i = 0; i < 4; ++i) {
        const int off = (tid + i * 256) * 16;
        load_lds16(wsrc + off, reinterpret_cast<char*>(Bs) + off);
      }
    }
    __builtin_amdgcn_sched_barrier(0);

    // ---- stage A tile k: convert pa_k (auto-wait skips the newer W ops)
    #pragma unroll
    for (int i = 0; i < 4; ++i) {
      const int ch  = tid + i * 256;
      const int row = ch >> 3;
      const int kg  = ch & 7;
      short8 sa;
      #pragma unroll
      for (int j = 0; j < 4; ++j) {
        sa[j]     = (short)f2bf(pa0[i][j]);
        sa[j + 4] = (short)f2bf(pa1[i][j]);
      }
      const int byte = row * 128 + ((kg * 16) ^ ((row & 7) << 4));
      *reinterpret_cast<short8*>(reinterpret_cast<char*>(As) + byte) = sa;
    }
    // issue next A tile's loads (k=3: redundant tile-0 -> uniform vmcnt(8))
    load_A(k < 3 ? (k + 1) * 64 : 0);

    asm volatile("s_waitcnt vmcnt(8) lgkmcnt(0)" ::: "memory");
    __builtin_amdgcn_sched_barrier(0);
    __builtin_amdgcn_s_barrier();
    __builtin_amdgcn_sched_barrier(0);

    // ---- MFMA phase
    #pragma unroll
    for (int ks = 0; ks < 2; ++ks) {
      const int kb = (ks * 32 + (lane >> 4) * 8) * 2;
      short8 af[4], bf[4];
      #pragma unroll
      for (int mi = 0; mi < 4; ++mi) {
        const int row = wm * 64 + mi * 16 + (lane & 15);
        const int byte = row * 128 + (kb ^ ((row & 7) << 4));
        af[mi] = *reinterpret_cast<const short8*>(
            reinterpret_cast<const char*>(As) + byte);
      }
      #pragma unroll
      for (int ni = 0; ni < 4; ++ni) {
        const int col = wn * 64 + ni * 16 + (lane & 15);
        const int byte = col * 128 + (kb ^ ((col & 7) << 4));
        bf[ni] = *reinterpret_cast<const short8*>(
            reinterpret_cast<const char*>(Bs) + byte);
      }
      #pragma unroll
      for (int mi = 0; mi < 4; ++mi)
        #pragma unroll
        for (int ni = 0; ni < 4; ++ni)
          acc[mi][ni] = __builtin_amdgcn_mfma_f32_16x16x32_bf16(
              af[mi], bf[ni], acc[mi][ni], 0, 0, 0);
    }

    asm volatile("s_waitcnt lgkmcnt(0)" ::: "memory");
    __builtin_amdgcn_sched_barrier(0);
    __builtin_amdgcn_s_barrier();
    __builtin_amdgcn_sched_barrier(0);
  }

  // epilogue: C/D layout col=lane&15, row=(lane>>4)*4+reg
  #pragma unroll
  for (int mi = 0; mi < 4; ++mi) {
    const int row = r0 + wm * 64 + mi * 16 + (lane >> 4) * 4;
    #pragma unroll
    for (int ni = 0; ni < 4; ++ni) {
      const int col = c0 + wn * 64 + ni * 16 + (lane & 15);
      #pragma unroll
      for (int j = 0; j < 4; ++j)
        out[(size_t)(row + j) * DM + col] = (_Float16)(acc[mi][ni][j] + bv[ni]);
    }
  }
}

// ---------------------------------------------------------------------------
// Sampler v4 (unchanged from round 5). Block = 512 threads = 8 queries,
// XCD-swizzled grid (n = blockIdx&7 -> batch slice L2-resident).
// Prep (t<256): (q,m,sub-level) -> 4-lane shfl softmax -> tap table in LDS.
// Gather: thread (q=wave, m, dg, th) does 8 taps; shfl_xor(4) partner merge.
// ---------------------------------------------------------------------------
__global__ __launch_bounds__(512) void sample_k(
    const _Float16* __restrict__ proj,    // (N*LQ, 256) f16
    const float* __restrict__ refp,       // (N, LQ, 4)
    const _Float16* __restrict__ value,   // (N, 3840, 256) f16, c = m*32+d
    float* __restrict__ out)              // (N, LQ, 256)
{
  __shared__ uint4 tap_s[8][136];   // [q][m*17 + tap], 17.4 KB

  const int d     = blockIdx.x;
  const int n     = d & 7;
  const int chunk = d >> 3;
  const int row0q = n * LQn + chunk * 8;
  const int t     = threadIdx.x;

  const int lens[4]   = {2048, 1024, 512, 256};
  const int starts[4] = {0, 2048, 3072, 3584};

  // ---- prep: softmax + tap table ----
  if (t < 256) {
    const int q   = t >> 5;
    const int m   = (t >> 2) & 7;
    const int sub = t & 3;              // == level l
    const int j0  = m * 16 + sub * 4;
    const size_t prow = (size_t)(row0q + q) * DM;

    const half4 offv = *reinterpret_cast<const half4*>(&proj[prow + j0]);
    const half4 lgv  = *reinterpret_cast<const half4*>(&proj[prow + 128 + j0]);
    float lg[4], off[4];
    #pragma unroll
    for (int i = 0; i < 4; ++i) { lg[i] = (float)lgv[i]; off[i] = (float)offv[i]; }

    float mx = fmaxf(fmaxf(lg[0], lg[1]), fmaxf(lg[2], lg[3]));
    mx = fmaxf(mx, __shfl_xor(mx, 1));
    mx = fmaxf(mx, __shfl_xor(mx, 2));
    float e[4], s = 0.f;
    #pragma unroll
    for (int i = 0; i < 4; ++i) { e[i] = __expf(lg[i] - mx); s += e[i]; }
    s += __shfl_xor(s, 1);
    s += __shfl_xor(s, 2);
    const float inv = 1.f / s;

    const int   T  = lens[sub];
    const int   st = starts[sub];
    const float fT = (float)T;
    const float rf = refp[(size_t)(row0q + q) * 4 + sub];
    #pragma unroll
    for (int i = 0; i < 4; ++i) {
      const float a  = e[i] * inv;
      const float ix = fmaf(rf, fT, off[i] - 0.5f);
      const float fl = floorf(ix);
      const float w1 = ix - fl;
      const int   i0 = (int)fl;
      const int   i1 = i0 + 1;
      const float wa = (i0 >= 0 && i0 < T) ? a * (1.f - w1) : 0.f;
      const float wb = (i1 >= 0 && i1 < T) ? a * w1 : 0.f;
      const int   r0b = (st + min(max(i0, 0), T - 1)) * 512;
      const int   r1b = (st + min(max(i1, 0), T - 1)) * 512;
      union { half2v h; unsigned u; } pw;
      pw.h.x = (_Float16)wa; pw.h.y = (_Float16)wb;
      uint4 ent; ent.x = pw.u; ent.y = (unsigned)r0b; ent.z = (unsigned)r1b; ent.w = 0u;
      tap_s[q][m * 17 + sub * 4 + i] = ent;
    }
  }
  __syncthreads();

  // ---- gather ----
  const int q  = t >> 6;          // wave id = query
  const int l  = t & 63;
  const int m  = l >> 3;
  const int dg = l & 3;
  const int th = (l >> 2) & 1;    // tap-half
  const char* vb = reinterpret_cast<const char*>(value) +
                   (size_t)n * S_TOT * 512 + m * 64 + dg * 16;

  float acc[8] = {};
  #pragma unroll
  for (int i = 0; i < 8; ++i) {
    const uint4 e = tap_s[q][m * 17 + th * 8 + i];
    union { unsigned u; half2v h; } pw; pw.u = e.x;
    const float wa = (float)pw.h.x;
    const float wb = (float)pw.h.y;
    const half8 v0 = *reinterpret_cast<const half8*>(vb + e.y);
    const half8 v1 = *reinterpret_cast<const half8*>(vb + e.z);
    #pragma unroll
    for (int j = 0; j < 8; ++j)
      acc[j] = fmaf(wa, (float)v0[j], fmaf(wb, (float)v1[j], acc[j]));
  }

  #pragma unroll
  for (int j = 0; j < 8; ++j) acc[j] += __shfl_xor(acc[j], 4);

  if (th == 0) {
    float* op = &out[(size_t)(row0q + q) * DM + m * 32 + dg * 8];
    f32x4 o0 = {acc[0], acc[1], acc[2], acc[3]};
    f32x4 o1 = {acc[4], acc[5], acc[6], acc[7]};
    *reinterpret_cast<f32x4*>(op)     = o0;
    *reinterpret_cast<f32x4*>(op + 4) = o1;
  }
}

}  // namespace

extern "C" void kernel_launch(void* const* d_in, const int* in_sizes, int n_in,
                              void* d_out, int out_size, void* d_ws, size_t ws_size,
                              hipStream_t stream) {
  const float* query  = (const float*)d_in[0];   // (8,2048,256)
  const float* refp   = (const float*)d_in[1];   // (8,2048,4,1)
  const float* inflat = (const float*)d_in[2];   // (8,3840,256)
  const float* W_val  = (const float*)d_in[5];   // (256,256)
  const float* b_val  = (const float*)d_in[6];   // (256,)
  const float* W_off  = (const float*)d_in[7];   // (128,256)
  const float* b_off  = (const float*)d_in[8];   // (128,)
  const float* W_attn = (const float*)d_in[9];   // (128,256)
  const float* b_attn = (const float*)d_in[10];  // (128,)
  float* out = (float*)d_out;

  // workspace: value f16 (15,728,640 B) | proj f16 (8,388,608 B) |
  //            W blob bf16 pre-swizzled (262,144 B)
  _Float16* value_h = (_Float16*)d_ws;
  _Float16* proj_h  = (_Float16*)((char*)d_ws + (size_t)15728640);
  unsigned short* wblob = (unsigned short*)((char*)d_ws + (size_t)24117248);

  // W f32 -> bf16 pre-swizzled blob (16 tiles x 16 KB)
  wconv_k<<<dim3(64), dim3(256), 0, stream>>>(W_val, W_off, W_attn, wblob);

  // merged GEMM: 480 value blocks + 256 proj blocks
  gemm_bf16_k<<<dim3(736), dim3(256), 0, stream>>>(
      inflat, query, wblob, b_val, b_off, b_attn, value_h, proj_h);

  // softmax + bilinear sampling + head-mix (XCD-swizzled grid)
  sample_k<<<dim3(NB * LQn / 8), dim3(512), 0, stream>>>(
      proj_h, refp, value_h, out);
}